// Round 5
// baseline (378.621 us; speedup 1.0000x reference)
//
#include <hip/hip_runtime.h>
#include <math.h>

// Problem constants (fixed by the reference)
#define SPATIAL (64*64*64)   // 262144 elements per (b, channel)
#define SPATIAL4 (SPATIAL/4) // 65536 float4 per channel
#define NCH 64
#define BN_EPS 1e-5f

// clang-native 4-float vector for nontemporal builtins
typedef float v4f __attribute__((ext_vector_type(4)));

// -------- Kernel 1: partial sums, FORCED depth-16 load pipelining ----------
// 2048 blocks x 256 threads, 8 blocks per (tensor,b,channel), each block a
// contiguous 32 KB eighth-channel. __launch_bounds__(256,4) gives the
// compiler a 128-VGPR budget so 16 independent in-flight v4f loads (64 VGPR
// of data) actually materialize — r3/r4's depth was silently clamped to
// 1-2 loads (VGPR=32/8), leaving every wave latency-bound. apply_kernel
// proves >4.2 TB/s is reachable with real depth; this copies its structure.
// g loads are nontemporal (keep x L3-resident); x loads allocate normally.
__global__ __launch_bounds__(256, 4) void mean_kernel(const float* __restrict__ g,
                                                      const float* __restrict__ x,
                                                      float* __restrict__ partial) {
    int blk = blockIdx.x;          // 0..2047
    int ch  = blk >> 3;            // 0..255 (0..127 = g channels, 128..255 = x)
    int oct = blk & 7;
    bool isg = ch < 128;
    const float* src = isg
        ? g + (size_t)ch * SPATIAL
        : x + (size_t)(ch - 128) * SPATIAL;
    const v4f* s4 = (const v4f*)src + (size_t)oct * 8192 + threadIdx.x;

    float a0 = 0.f, a1 = 0.f, a2 = 0.f, a3 = 0.f;
    v4f d[16];
    #pragma unroll
    for (int batch = 0; batch < 2; ++batch) {
        if (isg) {
            #pragma unroll
            for (int j = 0; j < 16; ++j)
                d[j] = __builtin_nontemporal_load(s4 + j * 256);
        } else {
            #pragma unroll
            for (int j = 0; j < 16; ++j)
                d[j] = s4[j * 256];
        }
        #pragma unroll
        for (int j = 0; j < 16; ++j) {
            float t = (d[j].x + d[j].y) + (d[j].z + d[j].w);
            if ((j & 3) == 0) a0 += t;
            else if ((j & 3) == 1) a1 += t;
            else if ((j & 3) == 2) a2 += t;
            else a3 += t;
        }
        s4 += 4096;
    }
    float sum = (a0 + a1) + (a2 + a3);

    // wave reduce (wave = 64)
    #pragma unroll
    for (int off = 32; off > 0; off >>= 1)
        sum += __shfl_down(sum, off, 64);
    __shared__ float wsum[4];
    int lane = threadIdx.x & 63, wave = threadIdx.x >> 6;
    if (lane == 0) wsum[wave] = sum;
    __syncthreads();
    if (threadIdx.x == 0)
        partial[blk] = wsum[0] + wsum[1] + wsum[2] + wsum[3];
}

// -------- Kernel 2: fold partials -> pooled, gating MLP -> 128 coefs -------
// 128 blocks (one per (b,gc)) x 64 threads (one per l). Coalesced w2 reads.
__global__ __launch_bounds__(64) void mlp_kernel(const float* __restrict__ partial,
                           const float* __restrict__ w1, const float* __restrict__ b1,
                           const float* __restrict__ w2, const float* __restrict__ b2,
                           const float* __restrict__ psi_w, const float* __restrict__ psi_b,
                           const float* __restrict__ bn_gamma, const float* __restrict__ bn_beta,
                           const float* __restrict__ bn_mean, const float* __restrict__ bn_var,
                           float* __restrict__ coef) {
    __shared__ float p[256];   // pooled, layout [b*128 + feature]
    __shared__ float h[32];    // hidden for this block's batch
    int tid = threadIdx.x;     // 0..63
    int blk = blockIdx.x;      // 0..127
    int b = blk >> 6, gc = blk & 63;

    // pooled: sum 8 partials per channel
    #pragma unroll
    for (int ch = tid; ch < 256; ch += 64) {
        const float* pp = partial + 8 * ch;
        float s = ((pp[0] + pp[1]) + (pp[2] + pp[3]))
                + ((pp[4] + pp[5]) + (pp[6] + pp[7]));
        int pi = (ch < 128) ? ((ch >> 6) * 128 + (ch & 63))
                            : (((ch - 128) >> 6) * 128 + 64 + ((ch - 128) & 63));
        p[pi] = s * (1.0f / SPATIAL);
    }
    __syncthreads();
    // hidden layer (redundant per block, cheap): threads 0..31
    if (tid < 32) {
        float acc = b1[tid];
        const float* wr = w1 + tid * 128;
        #pragma unroll 4
        for (int k = 0; k < 128; ++k) acc += p[b * 128 + k] * wr[k];
        h[tid] = fmaxf(acc, 0.f);
    }
    __syncthreads();
    // each thread: one l. w2 row contiguous 128B per lane, block reads 8KB.
    const float4* wr = (const float4*)(w2 + (size_t)(gc * 64 + tid) * 32);
    float z = b2[gc * 64 + tid];
    #pragma unroll
    for (int j = 0; j < 8; ++j) {
        float4 wv = wr[j];
        z += h[4*j] * wv.x + h[4*j+1] * wv.y + h[4*j+2] * wv.z + h[4*j+3] * wv.w;
    }
    float sig = 1.f / (1.f + expf(-z));   // dw[b,gc,l]
    float val = sig * psi_w[tid];
    #pragma unroll
    for (int off = 32; off > 0; off >>= 1)
        val += __shfl_down(val, off, 64);
    float scale = bn_gamma[0] * rsqrtf(bn_var[0] + BN_EPS);
    if (tid == 0) coef[b * 64 + gc] = val * scale;
    if (blk == 0 && tid == 0)
        coef[128] = (psi_b[0] - bn_mean[0]) * scale + bn_beta[0];
}

// -------- Kernel 3: s = sum_g g*c ; out = x * sigmoid(s + bias) ------------
// (unchanged — consistently the faster kernel, >4.2 TB/s effective)
__device__ __forceinline__ void fma4(v4f& a, v4f v, float c) {
    a.x += v.x * c; a.y += v.y * c; a.z += v.z * c; a.w += v.w * c;
}

__global__ __launch_bounds__(256, 8) void apply_kernel(const float* __restrict__ g,
                                                       const float* __restrict__ x,
                                                       const float* __restrict__ coef,
                                                       float* __restrict__ out) {
    int t    = threadIdx.x;
    int pos  = t & 63;
    int grp  = t >> 6;                        // 0..3
    int blk  = blockIdx.x;                    // 0..2047
    int batch = blk >> 10;                    // 1024 blocks per batch
    int base4 = (blk & 1023) * 64 + pos;      // float4 index within channel
    size_t bOff = (size_t)batch * NCH * SPATIAL4;

    const v4f* g4 = (const v4f*)g;
    const v4f* x4 = (const v4f*)x;
    v4f* o4 = (v4f*)out;

    const v4f* cfv = (const v4f*)(coef + batch * NCH + grp * 16);
    const v4f* gp = g4 + bOff + (size_t)(grp * 16) * SPATIAL4 + base4;

    v4f acc0 = {0.f,0.f,0.f,0.f}, acc1 = {0.f,0.f,0.f,0.f};
    #pragma unroll
    for (int bq = 0; bq < 4; ++bq) {          // 4 batches of 4 indep loads
        v4f cv = cfv[bq];
        v4f v0 = __builtin_nontemporal_load(gp + (size_t)(4*bq + 0) * SPATIAL4);
        v4f v1 = __builtin_nontemporal_load(gp + (size_t)(4*bq + 1) * SPATIAL4);
        v4f v2 = __builtin_nontemporal_load(gp + (size_t)(4*bq + 2) * SPATIAL4);
        v4f v3 = __builtin_nontemporal_load(gp + (size_t)(4*bq + 3) * SPATIAL4);
        fma4(acc0, v0, cv.x);
        fma4(acc1, v1, cv.y);
        fma4(acc0, v2, cv.z);
        fma4(acc1, v3, cv.w);
    }
    v4f acc = {acc0.x + acc1.x, acc0.y + acc1.y, acc0.z + acc1.z, acc0.w + acc1.w};

    __shared__ v4f red[4][64];
    if (grp != 0) red[grp][pos] = acc;
    __syncthreads();
    if (grp == 0) {
        v4f r1 = red[1][pos], r2 = red[2][pos], r3 = red[3][pos];
        float d = coef[128];
        v4f s;
        s.x = 1.f / (1.f + expf(-(acc.x + r1.x + r2.x + r3.x + d)));
        s.y = 1.f / (1.f + expf(-(acc.y + r1.y + r2.y + r3.y + d)));
        s.z = 1.f / (1.f + expf(-(acc.z + r1.z + r2.z + r3.z + d)));
        s.w = 1.f / (1.f + expf(-(acc.w + r1.w + r2.w + r3.w + d)));
        red[0][pos] = s;
    }
    __syncthreads();
    v4f s = red[0][pos];

    const v4f* xp = x4 + bOff + (size_t)(grp * 16) * SPATIAL4 + base4;
    v4f*       op = o4 + bOff + (size_t)(grp * 16) * SPATIAL4 + base4;
    #pragma unroll 4
    for (int l = 0; l < 16; ++l) {
        v4f xv = xp[(size_t)l * SPATIAL4];
        v4f ov = {xv.x * s.x, xv.y * s.y, xv.z * s.z, xv.w * s.w};
        __builtin_nontemporal_store(ov, op + (size_t)l * SPATIAL4);
    }
}

extern "C" void kernel_launch(void* const* d_in, const int* in_sizes, int n_in,
                              void* d_out, int out_size, void* d_ws, size_t ws_size,
                              hipStream_t stream) {
    const float* g        = (const float*)d_in[0];
    const float* x        = (const float*)d_in[1];
    const float* w1       = (const float*)d_in[2];
    const float* b1       = (const float*)d_in[3];
    const float* w2       = (const float*)d_in[4];
    const float* b2       = (const float*)d_in[5];
    const float* psi_w    = (const float*)d_in[6];
    const float* psi_b    = (const float*)d_in[7];
    const float* bn_gamma = (const float*)d_in[8];
    const float* bn_beta  = (const float*)d_in[9];
    const float* bn_mean  = (const float*)d_in[10];
    const float* bn_var   = (const float*)d_in[11];
    float* out = (float*)d_out;
    float* ws  = (float*)d_ws;

    float* partial = ws;         // 2048 floats
    float* coef    = ws + 2048;  // 129 floats

    mean_kernel<<<2048, 256, 0, stream>>>(g, x, partial);
    mlp_kernel<<<128, 64, 0, stream>>>(partial, w1, b1, w2, b2, psi_w, psi_b,
                                       bn_gamma, bn_beta, bn_mean, bn_var, coef);
    apply_kernel<<<2048, 256, 0, stream>>>(g, x, coef, out);
}

// Round 7
// 378.576 us; speedup vs baseline: 1.0001x; 1.0001x over previous
//
#include <hip/hip_runtime.h>
#include <math.h>

// Problem constants (fixed by the reference)
#define SPATIAL (64*64*64)   // 262144 elements per (b, channel)
#define SPATIAL4 (SPATIAL/4) // 65536 float4 per channel
#define NCH 64
#define BN_EPS 1e-5f

// clang-native 4-float vector for nontemporal builtins
typedef float v4f __attribute__((ext_vector_type(4)));

// -------- Kernel 1: partial sums, FENCED depth-16 load pipelining ----------
// 2048 blocks x 256 threads, 8 blocks per (tensor,b,channel); each block a
// contiguous 128 KB eighth-channel. Previous rounds' "deep" loads were
// silently collapsed to ~4 in flight (VGPR=32/8/40 in the dispatch CSV) --
// the scheduler sinks each load to its consume when nothing pins the order.
// __builtin_amdgcn_sched_barrier(0) after each 8-load group forbids that:
// 8-16 loads stay architecturally outstanding (64 B/lane), matching
// apply_kernel's structure (>=4.2 TB/s) instead of mean's 2.7 TB/s.
// Verification: VGPR_Count must come back ~80; if <=40 the fence failed.
__global__ __launch_bounds__(256, 4) void mean_kernel(const float* __restrict__ g,
                                                      const float* __restrict__ x,
                                                      float* __restrict__ partial) {
    int blk = blockIdx.x;          // 0..2047
    int ch  = blk >> 3;            // 0..255 (0..127 = g channels, 128..255 = x)
    int oct = blk & 7;
    const float* src = (ch < 128)
        ? g + (size_t)ch * SPATIAL
        : x + (size_t)(ch - 128) * SPATIAL;
    const v4f* s4 = (const v4f*)src + (size_t)oct * 8192 + threadIdx.x;

    v4f A0,A1,A2,A3,A4,A5,A6,A7;   // named regs: no dynamic indexing (scratch!)
    v4f B0,B1,B2,B3,B4,B5,B6,B7;
    float a0 = 0.f, a1 = 0.f, a2 = 0.f, a3 = 0.f;

#define LD8(R, base) \
    R##0 = __builtin_nontemporal_load((base) + 0*256);  \
    R##1 = __builtin_nontemporal_load((base) + 1*256);  \
    R##2 = __builtin_nontemporal_load((base) + 2*256);  \
    R##3 = __builtin_nontemporal_load((base) + 3*256);  \
    R##4 = __builtin_nontemporal_load((base) + 4*256);  \
    R##5 = __builtin_nontemporal_load((base) + 5*256);  \
    R##6 = __builtin_nontemporal_load((base) + 6*256);  \
    R##7 = __builtin_nontemporal_load((base) + 7*256);  \
    __builtin_amdgcn_sched_barrier(0);

// NOTE: member access must go through temps — R##0.x would lex "0.x" as one
// pp-number and the paste "A0.x" is an invalid token.
#define SUM8(R) { \
    v4f t0 = R##0, t1 = R##1, t2 = R##2, t3 = R##3; \
    v4f t4 = R##4, t5 = R##5, t6 = R##6, t7 = R##7; \
    a0 += (t0.x + t0.y) + (t0.z + t0.w); \
    a1 += (t1.x + t1.y) + (t1.z + t1.w); \
    a2 += (t2.x + t2.y) + (t2.z + t2.w); \
    a3 += (t3.x + t3.y) + (t3.z + t3.w); \
    a0 += (t4.x + t4.y) + (t4.z + t4.w); \
    a1 += (t5.x + t5.y) + (t5.z + t5.w); \
    a2 += (t6.x + t6.y) + (t6.z + t6.w); \
    a3 += (t7.x + t7.y) + (t7.z + t7.w); }

    LD8(A, s4)                 // batch 0 in flight (8)
    LD8(B, s4 + 2048)          // batch 1 in flight (16)
    SUM8(A)                    // waits vmcnt(8), B still in flight
    LD8(A, s4 + 4096)          // batch 2 in flight (16 again)
    SUM8(B)
    LD8(B, s4 + 6144)          // batch 3 in flight
    SUM8(A)
    SUM8(B)
#undef LD8
#undef SUM8

    float sum = (a0 + a1) + (a2 + a3);

    // wave reduce (wave = 64)
    #pragma unroll
    for (int off = 32; off > 0; off >>= 1)
        sum += __shfl_down(sum, off, 64);
    __shared__ float wsum[4];
    int lane = threadIdx.x & 63, wave = threadIdx.x >> 6;
    if (lane == 0) wsum[wave] = sum;
    __syncthreads();
    if (threadIdx.x == 0)
        partial[blk] = wsum[0] + wsum[1] + wsum[2] + wsum[3];
}

// -------- Kernel 2: fold partials -> pooled, gating MLP -> 128 coefs -------
// 128 blocks (one per (b,gc)) x 64 threads (one per l). Coalesced w2 reads.
__global__ __launch_bounds__(64) void mlp_kernel(const float* __restrict__ partial,
                           const float* __restrict__ w1, const float* __restrict__ b1,
                           const float* __restrict__ w2, const float* __restrict__ b2,
                           const float* __restrict__ psi_w, const float* __restrict__ psi_b,
                           const float* __restrict__ bn_gamma, const float* __restrict__ bn_beta,
                           const float* __restrict__ bn_mean, const float* __restrict__ bn_var,
                           float* __restrict__ coef) {
    __shared__ float p[256];   // pooled, layout [b*128 + feature]
    __shared__ float h[32];    // hidden for this block's batch
    int tid = threadIdx.x;     // 0..63
    int blk = blockIdx.x;      // 0..127
    int b = blk >> 6, gc = blk & 63;

    // pooled: sum 8 partials per channel
    #pragma unroll
    for (int ch = tid; ch < 256; ch += 64) {
        const float* pp = partial + 8 * ch;
        float s = ((pp[0] + pp[1]) + (pp[2] + pp[3]))
                + ((pp[4] + pp[5]) + (pp[6] + pp[7]));
        int pi = (ch < 128) ? ((ch >> 6) * 128 + (ch & 63))
                            : (((ch - 128) >> 6) * 128 + 64 + ((ch - 128) & 63));
        p[pi] = s * (1.0f / SPATIAL);
    }
    __syncthreads();
    // hidden layer (redundant per block, cheap): threads 0..31
    if (tid < 32) {
        float acc = b1[tid];
        const float* wr = w1 + tid * 128;
        #pragma unroll 4
        for (int k = 0; k < 128; ++k) acc += p[b * 128 + k] * wr[k];
        h[tid] = fmaxf(acc, 0.f);
    }
    __syncthreads();
    // each thread: one l. w2 row contiguous 128B per lane, block reads 8KB.
    const float4* wr = (const float4*)(w2 + (size_t)(gc * 64 + tid) * 32);
    float z = b2[gc * 64 + tid];
    #pragma unroll
    for (int j = 0; j < 8; ++j) {
        float4 wv = wr[j];
        z += h[4*j] * wv.x + h[4*j+1] * wv.y + h[4*j+2] * wv.z + h[4*j+3] * wv.w;
    }
    float sig = 1.f / (1.f + expf(-z));   // dw[b,gc,l]
    float val = sig * psi_w[tid];
    #pragma unroll
    for (int off = 32; off > 0; off >>= 1)
        val += __shfl_down(val, off, 64);
    float scale = bn_gamma[0] * rsqrtf(bn_var[0] + BN_EPS);
    if (tid == 0) coef[b * 64 + gc] = val * scale;
    if (blk == 0 && tid == 0)
        coef[128] = (psi_b[0] - bn_mean[0]) * scale + bn_beta[0];
}

// -------- Kernel 3: s = sum_g g*c ; out = x * sigmoid(s + bias) ------------
// (unchanged — consistently the faster kernel, >=4.2 TB/s effective)
__device__ __forceinline__ void fma4(v4f& a, v4f v, float c) {
    a.x += v.x * c; a.y += v.y * c; a.z += v.z * c; a.w += v.w * c;
}

__global__ __launch_bounds__(256, 8) void apply_kernel(const float* __restrict__ g,
                                                       const float* __restrict__ x,
                                                       const float* __restrict__ coef,
                                                       float* __restrict__ out) {
    int t    = threadIdx.x;
    int pos  = t & 63;
    int grp  = t >> 6;                        // 0..3
    int blk  = blockIdx.x;                    // 0..2047
    int batch = blk >> 10;                    // 1024 blocks per batch
    int base4 = (blk & 1023) * 64 + pos;      // float4 index within channel
    size_t bOff = (size_t)batch * NCH * SPATIAL4;

    const v4f* g4 = (const v4f*)g;
    const v4f* x4 = (const v4f*)x;
    v4f* o4 = (v4f*)out;

    const v4f* cfv = (const v4f*)(coef + batch * NCH + grp * 16);
    const v4f* gp = g4 + bOff + (size_t)(grp * 16) * SPATIAL4 + base4;

    v4f acc0 = {0.f,0.f,0.f,0.f}, acc1 = {0.f,0.f,0.f,0.f};
    #pragma unroll
    for (int bq = 0; bq < 4; ++bq) {          // 4 batches of 4 indep loads
        v4f cv = cfv[bq];
        v4f v0 = __builtin_nontemporal_load(gp + (size_t)(4*bq + 0) * SPATIAL4);
        v4f v1 = __builtin_nontemporal_load(gp + (size_t)(4*bq + 1) * SPATIAL4);
        v4f v2 = __builtin_nontemporal_load(gp + (size_t)(4*bq + 2) * SPATIAL4);
        v4f v3 = __builtin_nontemporal_load(gp + (size_t)(4*bq + 3) * SPATIAL4);
        fma4(acc0, v0, cv.x);
        fma4(acc1, v1, cv.y);
        fma4(acc0, v2, cv.z);
        fma4(acc1, v3, cv.w);
    }
    v4f acc = {acc0.x + acc1.x, acc0.y + acc1.y, acc0.z + acc1.z, acc0.w + acc1.w};

    __shared__ v4f red[4][64];
    if (grp != 0) red[grp][pos] = acc;
    __syncthreads();
    if (grp == 0) {
        v4f r1 = red[1][pos], r2 = red[2][pos], r3 = red[3][pos];
        float d = coef[128];
        v4f s;
        s.x = 1.f / (1.f + expf(-(acc.x + r1.x + r2.x + r3.x + d)));
        s.y = 1.f / (1.f + expf(-(acc.y + r1.y + r2.y + r3.y + d)));
        s.z = 1.f / (1.f + expf(-(acc.z + r1.z + r2.z + r3.z + d)));
        s.w = 1.f / (1.f + expf(-(acc.w + r1.w + r2.w + r3.w + d)));
        red[0][pos] = s;
    }
    __syncthreads();
    v4f s = red[0][pos];

    const v4f* xp = x4 + bOff + (size_t)(grp * 16) * SPATIAL4 + base4;
    v4f*       op = o4 + bOff + (size_t)(grp * 16) * SPATIAL4 + base4;
    #pragma unroll 4
    for (int l = 0; l < 16; ++l) {
        v4f xv = xp[(size_t)l * SPATIAL4];
        v4f ov = {xv.x * s.x, xv.y * s.y, xv.z * s.z, xv.w * s.w};
        __builtin_nontemporal_store(ov, op + (size_t)l * SPATIAL4);
    }
}

extern "C" void kernel_launch(void* const* d_in, const int* in_sizes, int n_in,
                              void* d_out, int out_size, void* d_ws, size_t ws_size,
                              hipStream_t stream) {
    const float* g        = (const float*)d_in[0];
    const float* x        = (const float*)d_in[1];
    const float* w1       = (const float*)d_in[2];
    const float* b1       = (const float*)d_in[3];
    const float* w2       = (const float*)d_in[4];
    const float* b2       = (const float*)d_in[5];
    const float* psi_w    = (const float*)d_in[6];
    const float* psi_b    = (const float*)d_in[7];
    const float* bn_gamma = (const float*)d_in[8];
    const float* bn_beta  = (const float*)d_in[9];
    const float* bn_mean  = (const float*)d_in[10];
    const float* bn_var   = (const float*)d_in[11];
    float* out = (float*)d_out;
    float* ws  = (float*)d_ws;

    float* partial = ws;         // 2048 floats
    float* coef    = ws + 2048;  // 129 floats

    mean_kernel<<<2048, 256, 0, stream>>>(g, x, partial);
    mlp_kernel<<<128, 64, 0, stream>>>(partial, w1, b1, w2, b2, psi_w, psi_b,
                                       bn_gamma, bn_beta, bn_mean, bn_var, coef);
    apply_kernel<<<2048, 256, 0, stream>>>(g, x, coef, out);
}

// Round 8
// 373.140 us; speedup vs baseline: 1.0147x; 1.0146x over previous
//
#include <hip/hip_runtime.h>
#include <math.h>

// Problem constants (fixed by the reference)
#define SPATIAL (64*64*64)   // 262144 elements per (b, channel)
#define SPATIAL4 (SPATIAL/4) // 65536 float4 per channel
#define NCH 64
#define BN_EPS 1e-5f

// clang-native 4-float vector for nontemporal builtins
typedef float v4f __attribute__((ext_vector_type(4)));

// -------- Kernel 1: channel-strided partial sums (mirror of apply) ---------
// r2-r7 evidence: apply (16 streams/thread, 1 MB apart) delivers 15.4
// GB/s/CU; every within-channel mean variant delivers 10.7 — same VGPR,
// same occupancy. So mean now copies apply's exact geometry: 2048 blocks
// x 256 threads; block owns 64 f4 positions; wave grp handles channels
// grp*16..+16; per thread 16 g-loads + 16 x-loads at SPATIAL4 stride.
// Per-channel sums via 64-lane shfl_xor butterfly; lane0 writes 32
// partials (static reg indexing only); fold_kernel reduces 1024 chunks.
__global__ __launch_bounds__(256) void mean_kernel(const float* __restrict__ g,
                                                   const float* __restrict__ x,
                                                   float* __restrict__ wpart) {
    int t     = threadIdx.x;
    int lane  = t & 63;
    int grp   = t >> 6;                 // 0..3 (== wave id)
    int blk   = blockIdx.x;             // 0..2047
    int batch = blk >> 10;              // 1024 blocks per batch
    int chunk = blk & 1023;
    int base4 = chunk * 64 + lane;      // f4 index within channel
    size_t bOff = (size_t)batch * NCH * SPATIAL4;

    const v4f* gp = (const v4f*)g + bOff + (size_t)(grp * 16) * SPATIAL4 + base4;
    const v4f* xp = (const v4f*)x + bOff + (size_t)(grp * 16) * SPATIAL4 + base4;

    // 16 g streams (nt: g cannot stay L3-resident anyway; don't evict x)
    float ga0,ga1,ga2,ga3,ga4,ga5,ga6,ga7,ga8,ga9,ga10,ga11,ga12,ga13,ga14,ga15;
    float xa0,xa1,xa2,xa3,xa4,xa5,xa6,xa7,xa8,xa9,xa10,xa11,xa12,xa13,xa14,xa15;
#define HS(v) ((v.x + v.y) + (v.z + v.w))
#define LDG(n) { v4f v = __builtin_nontemporal_load(gp + (size_t)(n) * SPATIAL4); ga##n = HS(v); }
#define LDX(n) { v4f v = xp[(size_t)(n) * SPATIAL4]; xa##n = HS(v); }
    LDG(0) LDG(1) LDG(2) LDG(3) LDG(4) LDG(5) LDG(6) LDG(7)
    LDG(8) LDG(9) LDG(10) LDG(11) LDG(12) LDG(13) LDG(14) LDG(15)
    LDX(0) LDX(1) LDX(2) LDX(3) LDX(4) LDX(5) LDX(6) LDX(7)
    LDX(8) LDX(9) LDX(10) LDX(11) LDX(12) LDX(13) LDX(14) LDX(15)
#undef LDG
#undef LDX
#undef HS

#define RED(v) { v += __shfl_xor(v, 32, 64); v += __shfl_xor(v, 16, 64); \
                 v += __shfl_xor(v,  8, 64); v += __shfl_xor(v,  4, 64); \
                 v += __shfl_xor(v,  2, 64); v += __shfl_xor(v,  1, 64); }
    RED(ga0) RED(ga1) RED(ga2) RED(ga3) RED(ga4) RED(ga5) RED(ga6) RED(ga7)
    RED(ga8) RED(ga9) RED(ga10) RED(ga11) RED(ga12) RED(ga13) RED(ga14) RED(ga15)
    RED(xa0) RED(xa1) RED(xa2) RED(xa3) RED(xa4) RED(xa5) RED(xa6) RED(xa7)
    RED(xa8) RED(xa9) RED(xa10) RED(xa11) RED(xa12) RED(xa13) RED(xa14) RED(xa15)
#undef RED

    // wpart row layout: [chunk][256 features]; feature = batch*64+c for g,
    // 128+batch*64+c for x. batch0/batch1 blocks write disjoint columns.
    if (lane == 0) {
        float* wr = wpart + (size_t)chunk * 256 + batch * 64 + grp * 16;
        wr[0]=ga0;  wr[1]=ga1;  wr[2]=ga2;  wr[3]=ga3;
        wr[4]=ga4;  wr[5]=ga5;  wr[6]=ga6;  wr[7]=ga7;
        wr[8]=ga8;  wr[9]=ga9;  wr[10]=ga10; wr[11]=ga11;
        wr[12]=ga12; wr[13]=ga13; wr[14]=ga14; wr[15]=ga15;
        float* wr2 = wr + 128;
        wr2[0]=xa0;  wr2[1]=xa1;  wr2[2]=xa2;  wr2[3]=xa3;
        wr2[4]=xa4;  wr2[5]=xa5;  wr2[6]=xa6;  wr2[7]=xa7;
        wr2[8]=xa8;  wr2[9]=xa9;  wr2[10]=xa10; wr2[11]=xa11;
        wr2[12]=xa12; wr2[13]=xa13; wr2[14]=xa14; wr2[15]=xa15;
    }
}

// -------- Kernel 1b: fold 1024 chunk-partials per feature -> pooled --------
// 256 blocks (one per feature) x 256 threads; reads 1 MB (L2-resident).
// Writes pooled[] already remapped to the MLP layout [b*128 + k], /SPATIAL.
__global__ __launch_bounds__(256) void fold_kernel(const float* __restrict__ wpart,
                                                   float* __restrict__ pooled) {
    int f   = blockIdx.x;         // 0..255 feature
    int tid = threadIdx.x;
    float s = 0.f;
    #pragma unroll
    for (int k = 0; k < 4; ++k)
        s += wpart[(size_t)(k * 256 + tid) * 256 + f];
    #pragma unroll
    for (int off = 32; off > 0; off >>= 1)
        s += __shfl_down(s, off, 64);
    __shared__ float ws[4];
    if ((tid & 63) == 0) ws[tid >> 6] = s;
    __syncthreads();
    if (tid == 0) {
        float tot = (ws[0] + ws[1]) + (ws[2] + ws[3]);
        int pi;
        if (f < 128) { int b = f >> 6, c = f & 63; pi = b * 128 + c; }
        else         { int b = (f - 128) >> 6, c = f & 63; pi = b * 128 + 64 + c; }
        pooled[pi] = tot * (1.0f / SPATIAL);
    }
}

// -------- Kernel 2: gating MLP -> 128 coefs + bias -------------------------
// 128 blocks (one per (b,gc)) x 64 threads (one per l). Coalesced w2 reads.
__global__ __launch_bounds__(64) void mlp_kernel(const float* __restrict__ pooled,
                           const float* __restrict__ w1, const float* __restrict__ b1,
                           const float* __restrict__ w2, const float* __restrict__ b2,
                           const float* __restrict__ psi_w, const float* __restrict__ psi_b,
                           const float* __restrict__ bn_gamma, const float* __restrict__ bn_beta,
                           const float* __restrict__ bn_mean, const float* __restrict__ bn_var,
                           float* __restrict__ coef) {
    __shared__ float p[256];   // pooled, layout [b*128 + feature]
    __shared__ float h[32];    // hidden for this block's batch
    int tid = threadIdx.x;     // 0..63
    int blk = blockIdx.x;      // 0..127
    int b = blk >> 6, gc = blk & 63;

    #pragma unroll
    for (int i = tid; i < 256; i += 64) p[i] = pooled[i];
    __syncthreads();
    // hidden layer (redundant per block, cheap): threads 0..31
    if (tid < 32) {
        float acc = b1[tid];
        const float* wr = w1 + tid * 128;
        #pragma unroll 4
        for (int k = 0; k < 128; ++k) acc += p[b * 128 + k] * wr[k];
        h[tid] = fmaxf(acc, 0.f);
    }
    __syncthreads();
    // each thread: one l. w2 row contiguous 128B per lane, block reads 8KB.
    const float4* wr = (const float4*)(w2 + (size_t)(gc * 64 + tid) * 32);
    float z = b2[gc * 64 + tid];
    #pragma unroll
    for (int j = 0; j < 8; ++j) {
        float4 wv = wr[j];
        z += h[4*j] * wv.x + h[4*j+1] * wv.y + h[4*j+2] * wv.z + h[4*j+3] * wv.w;
    }
    float sig = 1.f / (1.f + expf(-z));   // dw[b,gc,l]
    float val = sig * psi_w[tid];
    #pragma unroll
    for (int off = 32; off > 0; off >>= 1)
        val += __shfl_down(val, off, 64);
    float scale = bn_gamma[0] * rsqrtf(bn_var[0] + BN_EPS);
    if (tid == 0) coef[b * 64 + gc] = val * scale;
    if (blk == 0 && tid == 0)
        coef[128] = (psi_b[0] - bn_mean[0]) * scale + bn_beta[0];
}

// -------- Kernel 3: s = sum_g g*c ; out = x * sigmoid(s + bias) ------------
// (unchanged — consistently the faster kernel, 15.4 GB/s/CU combined)
__device__ __forceinline__ void fma4(v4f& a, v4f v, float c) {
    a.x += v.x * c; a.y += v.y * c; a.z += v.z * c; a.w += v.w * c;
}

__global__ __launch_bounds__(256, 8) void apply_kernel(const float* __restrict__ g,
                                                       const float* __restrict__ x,
                                                       const float* __restrict__ coef,
                                                       float* __restrict__ out) {
    int t    = threadIdx.x;
    int pos  = t & 63;
    int grp  = t >> 6;                        // 0..3
    int blk  = blockIdx.x;                    // 0..2047
    int batch = blk >> 10;                    // 1024 blocks per batch
    int base4 = (blk & 1023) * 64 + pos;      // float4 index within channel
    size_t bOff = (size_t)batch * NCH * SPATIAL4;

    const v4f* g4 = (const v4f*)g;
    const v4f* x4 = (const v4f*)x;
    v4f* o4 = (v4f*)out;

    const v4f* cfv = (const v4f*)(coef + batch * NCH + grp * 16);
    const v4f* gp = g4 + bOff + (size_t)(grp * 16) * SPATIAL4 + base4;

    v4f acc0 = {0.f,0.f,0.f,0.f}, acc1 = {0.f,0.f,0.f,0.f};
    #pragma unroll
    for (int bq = 0; bq < 4; ++bq) {          // 4 batches of 4 indep loads
        v4f cv = cfv[bq];
        v4f v0 = __builtin_nontemporal_load(gp + (size_t)(4*bq + 0) * SPATIAL4);
        v4f v1 = __builtin_nontemporal_load(gp + (size_t)(4*bq + 1) * SPATIAL4);
        v4f v2 = __builtin_nontemporal_load(gp + (size_t)(4*bq + 2) * SPATIAL4);
        v4f v3 = __builtin_nontemporal_load(gp + (size_t)(4*bq + 3) * SPATIAL4);
        fma4(acc0, v0, cv.x);
        fma4(acc1, v1, cv.y);
        fma4(acc0, v2, cv.z);
        fma4(acc1, v3, cv.w);
    }
    v4f acc = {acc0.x + acc1.x, acc0.y + acc1.y, acc0.z + acc1.z, acc0.w + acc1.w};

    __shared__ v4f red[4][64];
    if (grp != 0) red[grp][pos] = acc;
    __syncthreads();
    if (grp == 0) {
        v4f r1 = red[1][pos], r2 = red[2][pos], r3 = red[3][pos];
        float d = coef[128];
        v4f s;
        s.x = 1.f / (1.f + expf(-(acc.x + r1.x + r2.x + r3.x + d)));
        s.y = 1.f / (1.f + expf(-(acc.y + r1.y + r2.y + r3.y + d)));
        s.z = 1.f / (1.f + expf(-(acc.z + r1.z + r2.z + r3.z + d)));
        s.w = 1.f / (1.f + expf(-(acc.w + r1.w + r2.w + r3.w + d)));
        red[0][pos] = s;
    }
    __syncthreads();
    v4f s = red[0][pos];

    const v4f* xp = x4 + bOff + (size_t)(grp * 16) * SPATIAL4 + base4;
    v4f*       op = o4 + bOff + (size_t)(grp * 16) * SPATIAL4 + base4;
    #pragma unroll 4
    for (int l = 0; l < 16; ++l) {
        v4f xv = xp[(size_t)l * SPATIAL4];
        v4f ov = {xv.x * s.x, xv.y * s.y, xv.z * s.z, xv.w * s.w};
        __builtin_nontemporal_store(ov, op + (size_t)l * SPATIAL4);
    }
}

extern "C" void kernel_launch(void* const* d_in, const int* in_sizes, int n_in,
                              void* d_out, int out_size, void* d_ws, size_t ws_size,
                              hipStream_t stream) {
    const float* g        = (const float*)d_in[0];
    const float* x        = (const float*)d_in[1];
    const float* w1       = (const float*)d_in[2];
    const float* b1       = (const float*)d_in[3];
    const float* w2       = (const float*)d_in[4];
    const float* b2       = (const float*)d_in[5];
    const float* psi_w    = (const float*)d_in[6];
    const float* psi_b    = (const float*)d_in[7];
    const float* bn_gamma = (const float*)d_in[8];
    const float* bn_beta  = (const float*)d_in[9];
    const float* bn_mean  = (const float*)d_in[10];
    const float* bn_var   = (const float*)d_in[11];
    float* out = (float*)d_out;
    float* ws  = (float*)d_ws;

    float* wpart  = ws;                    // 1024*256 floats = 1 MB
    float* pooled = ws + 1024 * 256;       // 256 floats
    float* coef   = pooled + 256;          // 129 floats

    mean_kernel<<<2048, 256, 0, stream>>>(g, x, wpart);
    fold_kernel<<<256, 256, 0, stream>>>(wpart, pooled);
    mlp_kernel<<<128, 64, 0, stream>>>(pooled, w1, b1, w2, b2, psi_w, psi_b,
                                       bn_gamma, bn_beta, bn_mean, bn_var, coef);
    apply_kernel<<<2048, 256, 0, stream>>>(g, x, coef, out);
}